// Round 1
// baseline (75.770 us; speedup 1.0000x reference)
//
#include <hip/hip_runtime.h>
#include <stdint.h>

#define NB   64
#define NPIX 1024
#define DIM  768
#define KTOP 4
#define BIGL 1025   // N+1 sentinel, matches reference

// ---------------------------------------------------------------------------
// Kernel 1: sim[b,n] = dot(z[b,n,:], q[b,:]) / sqrt(768)
// One wave per row; lane reads float4 (16B) -> fully coalesced, 1 KiB/instr.
// fp64 accumulate, single rounding to fp32 (within 1 ulp of any ref order).
// ---------------------------------------------------------------------------
__global__ __launch_bounds__(256) void sgatt_sim(const float* __restrict__ z,
                                                 const float* __restrict__ q,
                                                 float* __restrict__ sim) {
    const int b    = blockIdx.y;
    const int lane = threadIdx.x & 63;
    const int wave = threadIdx.x >> 6;
    const float4* qv = reinterpret_cast<const float4*>(q + (size_t)b * DIM);
    const float4 q0 = qv[lane], q1 = qv[lane + 64], q2 = qv[lane + 128];
    const float rt = sqrtf((float)DIM);
#pragma unroll
    for (int r = 0; r < 4; ++r) {
        const int row = blockIdx.x * 16 + wave * 4 + r;
        const float4* zv =
            reinterpret_cast<const float4*>(z + (size_t)(b * NPIX + row) * DIM);
        const float4 z0 = zv[lane], z1 = zv[lane + 64], z2 = zv[lane + 128];
        double acc = (double)z0.x * q0.x + (double)z0.y * q0.y +
                     (double)z0.z * q0.z + (double)z0.w * q0.w;
        acc += (double)z1.x * q1.x + (double)z1.y * q1.y +
               (double)z1.z * q1.z + (double)z1.w * q1.w;
        acc += (double)z2.x * q2.x + (double)z2.y * q2.y +
               (double)z2.z * q2.z + (double)z2.w * q2.w;
#pragma unroll
        for (int o = 32; o > 0; o >>= 1) acc += __shfl_xor(acc, o);
        if (lane == 0) sim[b * NPIX + row] = (float)acc / rt;
    }
}

// ---------------------------------------------------------------------------
// Kernel 2: per-batch normalize -> Otsu -> CC label -> top-4 regions + bg.
// One block of 1024 threads per batch; everything lives in LDS.
// ---------------------------------------------------------------------------
__global__ __launch_bounds__(1024) void sgatt_region(const float* __restrict__ sim,
                                                     float* __restrict__ out) {
    const int b    = blockIdx.x;
    const int i    = threadIdx.x;
    const int lane = i & 63;
    const int wid  = i >> 6;

    __shared__ float s_sal[NPIX];
    __shared__ int   s_lab[NPIX];
    __shared__ int   s_hist[256];
    __shared__ float s_pmin[16], s_pmax[16];
    __shared__ float s_vval[256];
    __shared__ int   s_vidx[256];
    __shared__ int   s_area[NPIX + 1];
    __shared__ float s_ssum[NPIX + 1];
    __shared__ unsigned long long s_part[16];
    __shared__ unsigned long long s_win;
    __shared__ float s_smin, s_smax, s_mut;
    __shared__ int   s_chg;
    __shared__ int   s_top[KTOP];

    // ---- load sim, block min/max --------------------------------------
    const float sv = sim[b * NPIX + i];
    float mn = sv, mx = sv;
#pragma unroll
    for (int o = 32; o > 0; o >>= 1) {
        mn = fminf(mn, __shfl_xor(mn, o));
        mx = fmaxf(mx, __shfl_xor(mx, o));
    }
    if (lane == 0) { s_pmin[wid] = mn; s_pmax[wid] = mx; }
    __syncthreads();
    if (i == 0) {
        float a = s_pmin[0], c = s_pmax[0];
        for (int w = 1; w < 16; ++w) {
            a = fminf(a, s_pmin[w]);
            c = fmaxf(c, s_pmax[w]);
        }
        s_smin = a; s_smax = c;
    }
    __syncthreads();

    // ---- sal + u8 quantization (exact fp32 replication, no FMA) -------
    const float sal =
        __fdiv_rn(__fsub_rn(sv, s_smin),
                  __fadd_rn(__fsub_rn(s_smax, s_smin), 1e-6f));
    s_sal[i] = sal;
    int u8 = (int)floorf(__fmul_rn(sal, 255.0f));
    u8 = min(max(u8, 0), 255);

    // ---- histogram ----------------------------------------------------
    if (i < 256) s_hist[i] = 0;
    __syncthreads();
    atomicAdd(&s_hist[u8], 1);
    __syncthreads();

    // ---- Otsu: w0/mu cumsums are exact in fp32 (multiples of 2^-10,
    //      numerators < 2^24) so any summation order matches the ref.
    float w0 = 0.0f, mu = 0.0f;
    if (i < 256) {
        for (int j = 0; j <= i; ++j) {
            const float p = __fmul_rn((float)s_hist[j], 1.0f / 1024.0f);
            w0 = __fadd_rn(w0, p);
            mu = __fadd_rn(mu, __fmul_rn(p, (float)j));
        }
        if (i == 255) s_mut = mu;
    }
    __syncthreads();
    if (i < 256) {
        const float num = __fsub_rn(__fmul_rn(s_mut, w0), mu);
        const float den =
            __fadd_rn(__fmul_rn(w0, __fsub_rn(1.0f, w0)), 1e-12f);
        s_vval[i] = __fdiv_rn(__fmul_rn(num, num), den);
        s_vidx[i] = i;
    }
    __syncthreads();
    // argmax, first-index tie-break (matches jnp.argmax)
    for (int s = 128; s > 0; s >>= 1) {
        if (i < s) {
            const float va = s_vval[i], vb = s_vval[i + s];
            const int   ia = s_vidx[i], ib = s_vidx[i + s];
            if (vb > va || (vb == va && ib < ia)) {
                s_vval[i] = vb; s_vidx[i] = ib;
            }
        }
        __syncthreads();
    }
    const int thr = s_vidx[0];

    // ---- binary mask + CC labeling (min-propagation + pointer jumping)
    const int m = (u8 > thr) ? 1 : 0;
    s_lab[i] = m ? (i + 1) : BIGL;
    if (i == 0) s_chg = 0;
    __syncthreads();

    const int r = i >> 5, c = i & 31;
    for (int it = 0; it < 2048; ++it) {
        const int old = s_lab[i];
        int nl = old;
        if (m) {
            int mv = old;
            if (r > 0) {
                if (c > 0)  mv = min(mv, s_lab[i - 33]);
                mv = min(mv, s_lab[i - 32]);
                if (c < 31) mv = min(mv, s_lab[i - 31]);
            }
            if (c > 0)  mv = min(mv, s_lab[i - 1]);
            if (c < 31) mv = min(mv, s_lab[i + 1]);
            if (r < 31) {
                if (c > 0)  mv = min(mv, s_lab[i + 31]);
                mv = min(mv, s_lab[i + 32]);
                if (c < 31) mv = min(mv, s_lab[i + 33]);
            }
            // pointer jumping: labels always point at a same-component pixel
            mv = min(mv, s_lab[mv - 1]);
            mv = min(mv, s_lab[mv - 1]);
            nl = mv;
        }
        __syncthreads();
        if (nl != old) { s_lab[i] = nl; s_chg = 1; }
        __syncthreads();
        const int done = (s_chg == 0);
        __syncthreads();
        if (i == 0) s_chg = 0;
        __syncthreads();
        if (done) break;
    }

    // ---- per-component area / sal-sum ---------------------------------
    s_area[i] = 0; s_ssum[i] = 0.0f;
    if (i == 0) { s_area[NPIX] = 0; s_ssum[NPIX] = 0.0f; }
    __syncthreads();
    const int labi = m ? s_lab[i] : 0;
    if (m) {
        atomicAdd(&s_area[labi], 1);
        atomicAdd(&s_ssum[labi], s_sal[i]);
    }
    __syncthreads();

    // ---- candidate key: thread i owns label L=i+1 ----------------------
    // valid <=> area >= 20.48 <=> area >= 21 (area integral); mean > 0 so
    // float bits are order-preserving; ~L in low word => ties pick lower L
    // (lax.top_k stable tie-break).
    const int L = i + 1;
    const int a = s_area[L];
    unsigned long long key = 0ull;
    if (a >= 21) {
        const float mean = __fdiv_rn(s_ssum[L], (float)a);
        const unsigned int mb = __float_as_uint(mean);
        key = ((unsigned long long)mb << 32) |
              (unsigned long long)(0xFFFFFFFFu - (unsigned)L);
    }

    // ---- top-4 by repeated block max ----------------------------------
    for (int k = 0; k < KTOP; ++k) {
        unsigned long long v = key;
#pragma unroll
        for (int o = 32; o > 0; o >>= 1) {
            const unsigned long long w = __shfl_xor(v, o);
            if (w > v) v = w;
        }
        if (lane == 0) s_part[wid] = v;
        __syncthreads();
        if (i == 0) {
            unsigned long long bb = s_part[0];
            for (int w2 = 1; w2 < 16; ++w2)
                if (s_part[w2] > bb) bb = s_part[w2];
            s_win = bb;
        }
        __syncthreads();
        const unsigned long long win = s_win;
        if (i == 0) {
            s_top[k] = (win != 0ull)
                           ? (int)(0xFFFFFFFFu - (unsigned)(win & 0xFFFFFFFFull))
                           : -1;
        }
        if (key == win && key != 0ull) key = 0ull;  // remove unique winner
        __syncthreads();
    }

    // ---- write regions + background -----------------------------------
    float* ob = out + (size_t)b * 5 * NPIX;
    int anyr = 0;
#pragma unroll
    for (int k = 0; k < KTOP; ++k) {
        const int tl = s_top[k];
        const int match = (tl >= 0 && labi == tl) ? 1 : 0;
        anyr |= match;
        ob[k * NPIX + i] = (float)match;
    }
    ob[KTOP * NPIX + i] = anyr ? 0.0f : 1.0f;
}

// ---------------------------------------------------------------------------
extern "C" void kernel_launch(void* const* d_in, const int* in_sizes, int n_in,
                              void* d_out, int out_size, void* d_ws, size_t ws_size,
                              hipStream_t stream) {
    const float* z = (const float*)d_in[0];
    const float* q = (const float*)d_in[1];
    float* out = (float*)d_out;
    float* sim = (float*)d_ws;  // NB*NPIX floats = 256 KiB

    dim3 g1(NPIX / 16, NB);
    sgatt_sim<<<g1, 256, 0, stream>>>(z, q, sim);
    sgatt_region<<<NB, NPIX, 0, stream>>>(sim, out);
}